// Round 15
// baseline (157.678 us; speedup 1.0000x reference)
//
#include <hip/hip_runtime.h>
#include <hip/hip_bf16.h>
#include <cstdint>
#include <cstddef>

// ---------------- types / helpers ----------------
typedef float  f32x4  __attribute__((ext_vector_type(4)));
typedef __bf16 bf16x8 __attribute__((ext_vector_type(8)));
typedef unsigned short u16x8 __attribute__((ext_vector_type(8)));

__device__ __forceinline__ unsigned short f2bf(float f) {
    unsigned u = __float_as_uint(f);
    u += 0x7FFFu + ((u >> 16) & 1u);   // round-to-nearest-even
    return (unsigned short)(u >> 16);
}

// ---------------- problem constants ----------------
// B=64, C=80, IN_CH=300, J=8192, S=8, OUT=1024
// feature [64,2048,14,14] (131072 rows of 196 floats), out [64,80]

// ---------------- ws layout (bytes) ----------------
constexpr size_t OFF_FEATB = 0;          // 64*2048 bf16  = 262144
constexpr size_t OFF_X2B   = 262144;     // 80*1024 bf16  = 163840
constexpr size_t OFF_XB    = 425984;     // 80*2048 bf16  = 327680
constexpr size_t OFF_IMG   = 753664;     // 64*8192 f32   = 2097152
constexpr size_t OFF_CLS   = 2850816;    // 80*8192 f32   = 2621440
constexpr size_t OFF_G     = 5472256;    // 80*8192 f32   = 2621440

// =================== kA roles (256 threads) ===================

// maxpool (R13 LDS-linear, proven): block copies 32 rows = 25088 B flat
// (lane i <-> float4 i), then reduces from LDS. Bit-identical max.
__device__ __forceinline__ void maxpool_role(int vbid, const float* __restrict__ feature,
                                             unsigned short* __restrict__ featb,
                                             float4* tile /* 1568 float4 */) {
    int t = threadIdx.x;
    const float4* src = (const float4*)(feature + (size_t)vbid * 32 * 196);
    #pragma unroll
    for (int pass = 0; pass < 6; ++pass)
        tile[pass * 256 + t] = src[pass * 256 + t];
    if (t < 32) tile[1536 + t] = src[1536 + t];
    __syncthreads();

    int r = t >> 3, q = t & 7;                    // 32 rows x 8 threads
    const float4* row = tile + r * 49;
    float4 v0 = row[q],      v1 = row[q + 8],  v2 = row[q + 16];
    float4 v3 = row[q + 24], v4 = row[q + 32], v5 = row[q + 40];
    float m0 = fmaxf(fmaxf(v0.x, v0.y), fmaxf(v0.z, v0.w));
    float m1 = fmaxf(fmaxf(v1.x, v1.y), fmaxf(v1.z, v1.w));
    float m2 = fmaxf(fmaxf(v2.x, v2.y), fmaxf(v2.z, v2.w));
    float m3 = fmaxf(fmaxf(v3.x, v3.y), fmaxf(v3.z, v3.w));
    float m4 = fmaxf(fmaxf(v4.x, v4.y), fmaxf(v4.z, v4.w));
    float m5 = fmaxf(fmaxf(v5.x, v5.y), fmaxf(v5.z, v5.w));
    float m = fmaxf(fmaxf(fmaxf(m0, m1), fmaxf(m2, m3)), fmaxf(m4, m5));
    if (q == 0) {
        float4 d = row[48];
        m = fmaxf(m, fmaxf(fmaxf(d.x, d.y), fmaxf(d.z, d.w)));
    }
    #pragma unroll
    for (int off = 1; off < 8; off <<= 1) m = fmaxf(m, __shfl_xor(m, off));
    if (q == 0) featb[vbid * 32 + r] = f2bf(m);
}

// GCN-front r15: FULLY block-self-contained (y0 -> x1 -> x2 in one block).
// 64 blocks, each owns a 16-column j-slice. The y0 K=300 loop reads W1^T and
// inp from LDS as float4 (no serial global chains — the R7/R10 disease).
// Layout (floats): W1sT[16][304] @0 | inpS[16][304] @4864 | y0s[80][16] @9728
//                  x1s[80][16] @11008 | dinv[80] @12288   (total 12368 = 49.5 KB)
__device__ __forceinline__ void gcn_front_role(int idx, const float* __restrict__ inp,
                                               const float* __restrict__ W1,
                                               const float* __restrict__ A,
                                               unsigned short* __restrict__ x2b,
                                               float* smem) {
    float* W1sT = smem;            // [16 j][304 k]
    float* inpS = smem + 4864;     // [16 c][304 k]
    float* y0s  = smem + 9728;     // [80][16]
    float* x1s  = smem + 11008;    // [80][16]
    float* dinv = smem + 12288;    // [80]
    int t = threadIdx.x;
    int jj = t & 15, cg = t >> 4;                 // 16 x 16
    int j0 = idx * 16;

    if (t < 80) {
        const float4* ar = (const float4*)(A + t * 80);
        float4 s4 = {0.f, 0.f, 0.f, 0.f};
        #pragma unroll
        for (int q = 0; q < 20; q++) {
            float4 v = ar[q];
            s4.x += v.x; s4.y += v.y; s4.z += v.z; s4.w += v.w;
        }
        dinv[t] = 1.0f / sqrtf(s4.x + s4.y + s4.z + s4.w);
    }
    // stage W1^T slice: W1sT[j][k] = W1[k][j0+j]
    for (int i = t; i < 300 * 16; i += 256) {
        int k = i >> 4, j = i & 15;
        W1sT[j * 304 + k] = W1[(size_t)k * 1024 + j0 + j];
    }

    // y0 in 5 chunks of 16 c; thread (cg,jj) owns c = ch*16+cg over full K.
    for (int ch = 0; ch < 5; ++ch) {
        __syncthreads();                          // W1sT ready / prev compute done
        for (int i = t; i < 16 * 300; i += 256) {
            int c = i / 300, k = i - c * 300;
            inpS[c * 304 + k] = inp[(size_t)(ch * 16 + c) * 300 + k];
        }
        __syncthreads();
        const float4* ip4 = (const float4*)(inpS + cg * 304);
        const float4* wp4 = (const float4*)(W1sT + jj * 304);
        float4 a = {0.f, 0.f, 0.f, 0.f};
        #pragma unroll 5
        for (int k4 = 0; k4 < 75; ++k4) {
            float4 iv = ip4[k4], wv = wp4[k4];
            a.x = fmaf(iv.x, wv.x, a.x);
            a.y = fmaf(iv.y, wv.y, a.y);
            a.z = fmaf(iv.z, wv.z, a.z);
            a.w = fmaf(iv.w, wv.w, a.w);
        }
        y0s[(ch * 16 + cg) * 16 + jj] = (a.x + a.y) + (a.z + a.w);
    }
    __syncthreads();                              // y0s + dinv complete

    // ys = dinv * y0 (thread-local c ownership matches writer)
    #pragma unroll
    for (int rep = 0; rep < 5; ++rep) {
        int c = rep * 16 + cg;
        y0s[c * 16 + jj] *= dinv[c];
    }
    __syncthreads();

    // x1s[c][j] = dinv[c] * leaky(dinv[c] applied) ... exact proven math:
    // b = sum_e A[e,c]*ys[e]; b *= dinv[c]; leaky; store xs = dinv[c]*b
    #pragma unroll
    for (int rep = 0; rep < 5; ++rep) {
        int c = rep * 16 + cg;
        float b = 0.f;
        #pragma unroll 4
        for (int e = 0; e < 80; e++)
            b = fmaf(A[e * 80 + c], y0s[e * 16 + jj], b);
        b *= dinv[c];
        if (b < 0.f) b *= 0.2f;
        x1s[c * 16 + jj] = dinv[c] * b;
    }
    __syncthreads();

    // x2 = dinv[c] * sum_e A[e,c]*xs[e] -> bf16 global
    #pragma unroll
    for (int rep = 0; rep < 5; ++rep) {
        int c = rep * 16 + cg;
        float d = 0.f;
        #pragma unroll 4
        for (int e = 0; e < 80; e++)
            d = fmaf(A[e * 80 + c], x1s[e * 16 + jj], d);
        x2b[c * 1024 + j0 + jj] = f2bf(d * dinv[c]);
    }
}

// =================== MFMA GEMMs (256 thr, BN=16, in-block 4-way K-split) ===================
template <int MF>
__device__ __forceinline__ void gemm_block(int bx, const unsigned short* __restrict__ X,
                                           const float* __restrict__ W,
                                           const float* __restrict__ bias,
                                           float* __restrict__ outf,
                                           unsigned short* __restrict__ outb,
                                           int N, int K, float (*red)[64][21]) {
    int tid = threadIdx.x;
    int ks = tid >> 6, lane = tid & 63;
    int n = bx * 16 + (lane & 15);
    int rowa = lane & 15;
    int koff = (lane >> 4) * 8;
    int Kc = K >> 2;
    int k0 = ks * Kc;

    f32x4 acc[MF];
    #pragma unroll
    for (int i = 0; i < MF; i++) acc[i] = (f32x4)(0.f);

    const float* wrow = W + (size_t)n * K;

    #pragma unroll 2
    for (int k = k0; k < k0 + Kc; k += 32) {
        float4 w0 = *(const float4*)(wrow + k + koff);
        float4 w1 = *(const float4*)(wrow + k + koff + 4);
        u16x8 bu;
        bu[0] = f2bf(w0.x); bu[1] = f2bf(w0.y); bu[2] = f2bf(w0.z); bu[3] = f2bf(w0.w);
        bu[4] = f2bf(w1.x); bu[5] = f2bf(w1.y); bu[6] = f2bf(w1.z); bu[7] = f2bf(w1.w);
        bf16x8 bf = __builtin_bit_cast(bf16x8, bu);
        #pragma unroll
        for (int mf = 0; mf < MF; mf++) {
            u16x8 au = *(const u16x8*)(X + (size_t)(mf * 16 + rowa) * K + k + koff);
            acc[mf] = __builtin_amdgcn_mfma_f32_16x16x32_bf16(
                __builtin_bit_cast(bf16x8, au), bf, acc[mf], 0, 0, 0);
        }
    }

    #pragma unroll
    for (int mf = 0; mf < MF; mf++)
        #pragma unroll
        for (int i = 0; i < 4; i++)
            red[ks][lane][mf * 4 + i] = acc[mf][i];
    __syncthreads();

    int lane2 = tid & 63, sg = tid >> 6;
    int n2 = bx * 16 + (lane2 & 15);
    float b = bias ? bias[n2] : 0.f;
    #pragma unroll
    for (int mf = 0; mf < MF; mf++) {
        int slot = mf * 4 + sg;
        float s = red[0][lane2][slot] + red[1][lane2][slot]
                + red[2][lane2][slot] + red[3][lane2][slot] + b;
        int row = mf * 16 + (lane2 >> 4) * 4 + sg;
        size_t o = (size_t)row * N + n2;
        if (outf) outf[o] = s;
        if (outb) outb[o] = f2bf(s);
    }
}

// W in [K][N] row-major: strided B loads — no transpose needed.
template <int MF>
__device__ __forceinline__ void gemm_block_kn(int bx, const unsigned short* __restrict__ X,
                                              const float* __restrict__ Wkn,
                                              const float* __restrict__ bias,
                                              float* __restrict__ outf,
                                              unsigned short* __restrict__ outb,
                                              int N, int K, float (*red)[64][21]) {
    int tid = threadIdx.x;
    int ks = tid >> 6, lane = tid & 63;
    int n = bx * 16 + (lane & 15);
    int rowa = lane & 15;
    int koff = (lane >> 4) * 8;
    int Kc = K >> 2;
    int k0 = ks * Kc;

    f32x4 acc[MF];
    #pragma unroll
    for (int i = 0; i < MF; i++) acc[i] = (f32x4)(0.f);

    #pragma unroll 2
    for (int k = k0; k < k0 + Kc; k += 32) {
        float w[8];
        #pragma unroll
        for (int i = 0; i < 8; i++) w[i] = Wkn[(size_t)(k + koff + i) * N + n];
        u16x8 bu;
        #pragma unroll
        for (int i = 0; i < 8; i++) bu[i] = f2bf(w[i]);
        bf16x8 bf = __builtin_bit_cast(bf16x8, bu);
        #pragma unroll
        for (int mf = 0; mf < MF; mf++) {
            u16x8 au = *(const u16x8*)(X + (size_t)(mf * 16 + rowa) * K + k + koff);
            acc[mf] = __builtin_amdgcn_mfma_f32_16x16x32_bf16(
                __builtin_bit_cast(bf16x8, au), bf, acc[mf], 0, 0, 0);
        }
    }

    #pragma unroll
    for (int mf = 0; mf < MF; mf++)
        #pragma unroll
        for (int i = 0; i < 4; i++)
            red[ks][lane][mf * 4 + i] = acc[mf][i];
    __syncthreads();

    int lane2 = tid & 63, sg = tid >> 6;
    int n2 = bx * 16 + (lane2 & 15);
    float b = bias ? bias[n2] : 0.f;
    #pragma unroll
    for (int mf = 0; mf < MF; mf++) {
        int slot = mf * 4 + sg;
        float s = red[0][lane2][slot] + red[1][lane2][slot]
                + red[2][lane2][slot] + red[3][lane2][slot] + b;
        int row = mf * 16 + (lane2 >> 4) * 4 + sg;
        size_t o = (size_t)row * N + n2;
        if (outf) outf[o] = s;
        if (outb) outb[o] = f2bf(s);
    }
}

// =================== kernels (5 dispatches) ===================

// A: gcn-front self-contained (0-63) | maxpool (64-4159)
__global__ __launch_bounds__(256, 2) void kA(const float* __restrict__ feature,
                                             unsigned short* __restrict__ featb,
                                             const float* __restrict__ inp,
                                             const float* __restrict__ W1,
                                             const float* __restrict__ A,
                                             unsigned short* __restrict__ x2b) {
    __shared__ __align__(16) float smem[12368];   // 49.5 KB union
    int b = blockIdx.x;
    if (b < 64) gcn_front_role(b, inp, W1, A, x2b, smem);
    else        maxpool_role(b - 64, feature, featb, (float4*)smem);
}

// B: img all (0-511) | xb (512-639)
__global__ __launch_bounds__(256, 4) void kB(const unsigned short* __restrict__ featb,
                                             const float* __restrict__ W_img,
                                             const float* __restrict__ b_img,
                                             float* __restrict__ img,
                                             const unsigned short* __restrict__ x2b,
                                             const float* __restrict__ W_gc2,
                                             unsigned short* __restrict__ xb) {
    __shared__ __align__(16) float red[4][64][21];   // 21.5 KB
    int b = blockIdx.x;
    if (b < 512) gemm_block<4>(b, featb, W_img, b_img, img, nullptr, 8192, 2048, red);
    else         gemm_block_kn<5>(b - 512, x2b, W_gc2, nullptr, nullptr, xb, 2048, 1024, red);
}

// C: cls = xb @ W_cls^T + b_cls (512 blocks)
__global__ __launch_bounds__(256, 4) void kC(const unsigned short* __restrict__ xb,
                                             const float* __restrict__ W_cls,
                                             const float* __restrict__ b_cls,
                                             float* __restrict__ cls) {
    __shared__ __align__(16) float red[4][64][21];
    gemm_block<5>(blockIdx.x, xb, W_cls, b_cls, cls, nullptr, 8192, 2048, red);
}

// D: G[c2,j] = sum_c cls[c,j] * W_ml[c2, c*1024 + (j>>3)]; 640 blocks
__global__ __launch_bounds__(256, 4) void kD(const float* __restrict__ cls,
                                             const float* __restrict__ W_ml,
                                             float* __restrict__ G) {
    __shared__ __align__(16) float smem[8 * 80 * 16];   // 40 KB
    float (*wml)[80][16] = (float (*)[80][16])smem;
    int idx = blockIdx.x;
    int o0  = (idx & 63) * 16;
    int c2b = (idx >> 6) * 8;
    int j0  = o0 * 8;
    for (int i = threadIdx.x; i < 8 * 80 * 16; i += 256) {
        int ol = i & 15, c = (i >> 4) % 80, c2 = i / 1280;
        wml[c2][c][ol] = W_ml[(size_t)(c2b + c2) * 81920 + c * 1024 + o0 + ol];
    }
    __syncthreads();
    int jl  = threadIdx.x & 127;
    int c2h = (threadIdx.x >> 7) * 4;
    int ol  = jl >> 3;
    float acc[4] = {0.f, 0.f, 0.f, 0.f};
    for (int c = 0; c < 80; c++) {
        float cv = cls[(size_t)c * 8192 + j0 + jl];
        #pragma unroll
        for (int i = 0; i < 4; i++) acc[i] = fmaf(cv, wml[c2h + i][c][ol], acc[i]);
    }
    #pragma unroll
    for (int i = 0; i < 4; i++) G[(size_t)(c2b + c2h + i) * 8192 + j0 + jl] = acc[i];
}

// E: out[b,c2] = sum_j img[b,j]*G[c2,j] + b_ml[c2]; 640 blocks
__global__ __launch_bounds__(256, 2) void kE(const float* __restrict__ img,
                                             const float* __restrict__ G,
                                             const float* __restrict__ b_ml,
                                             float* __restrict__ out) {
    __shared__ float sm[4][8];
    int b = blockIdx.x / 10, cg = blockIdx.x % 10;
    int kc = threadIdx.x >> 6, lane = threadIdx.x & 63;
    const float* ib = img + (size_t)b * 8192 + kc * 2048;
    const float* gb = G + (size_t)(cg * 8) * 8192 + kc * 2048;
    float acc[8] = {0.f, 0.f, 0.f, 0.f, 0.f, 0.f, 0.f, 0.f};
    #pragma unroll
    for (int step = 0; step < 8; step++) {
        int k = step * 256 + lane * 4;
        float4 iv = *(const float4*)(ib + k);
        float4 gv[8];
        #pragma unroll
        for (int i = 0; i < 8; i++) gv[i] = *(const float4*)(gb + (size_t)i * 8192 + k);
        #pragma unroll
        for (int i = 0; i < 8; i++) {
            acc[i] = fmaf(iv.x, gv[i].x, acc[i]);
            acc[i] = fmaf(iv.y, gv[i].y, acc[i]);
            acc[i] = fmaf(iv.z, gv[i].z, acc[i]);
            acc[i] = fmaf(iv.w, gv[i].w, acc[i]);
        }
    }
    #pragma unroll
    for (int i = 0; i < 8; i++) {
        float v = acc[i];
        #pragma unroll
        for (int off = 32; off; off >>= 1) v += __shfl_xor(v, off);
        if (lane == 0) sm[kc][i] = v;
    }
    __syncthreads();
    if (threadIdx.x < 8) {
        int i = threadIdx.x;
        float s = b_ml[cg * 8 + i] + sm[0][i] + sm[1][i] + sm[2][i] + sm[3][i];
        out[(size_t)b * 80 + cg * 8 + i] = s;
    }
}

// ---------------- launch ----------------
extern "C" void kernel_launch(void* const* d_in, const int* in_sizes, int n_in,
                              void* d_out, int out_size, void* d_ws, size_t ws_size,
                              hipStream_t stream) {
    (void)in_sizes; (void)n_in; (void)out_size; (void)ws_size;
    const float* feature = (const float*)d_in[0];
    const float* inp     = (const float*)d_in[1];
    const float* A       = (const float*)d_in[2];
    const float* W_gc1   = (const float*)d_in[3];
    const float* W_gc2   = (const float*)d_in[4];
    const float* W_img   = (const float*)d_in[5];
    const float* b_img   = (const float*)d_in[6];
    const float* W_cls   = (const float*)d_in[7];
    const float* b_cls   = (const float*)d_in[8];
    const float* W_ml    = (const float*)d_in[9];
    const float* b_ml    = (const float*)d_in[10];
    float* out = (float*)d_out;
    char*  ws  = (char*)d_ws;

    unsigned short* featb = (unsigned short*)(ws + OFF_FEATB);
    unsigned short* x2b   = (unsigned short*)(ws + OFF_X2B);
    unsigned short* xb    = (unsigned short*)(ws + OFF_XB);
    float* img  = (float*)(ws + OFF_IMG);
    float* cls  = (float*)(ws + OFF_CLS);
    float* G    = (float*)(ws + OFF_G);

    kA<<<4160, 256, 0, stream>>>(feature, featb, inp, W_gc1, A, x2b);
    kB<<<640,  256, 0, stream>>>(featb, W_img, b_img, img, x2b, W_gc2, xb);
    kC<<<512,  256, 0, stream>>>(xb, W_cls, b_cls, cls);
    kD<<<640,  256, 0, stream>>>(cls, W_ml, G);
    kE<<<640,  256, 0, stream>>>(img, G, b_ml, out);
}

// Round 16
// 132.516 us; speedup vs baseline: 1.1899x; 1.1899x over previous
//
#include <hip/hip_runtime.h>
#include <hip/hip_bf16.h>
#include <cstdint>
#include <cstddef>

// ---------------- types / helpers ----------------
typedef float  f32x4  __attribute__((ext_vector_type(4)));
typedef __bf16 bf16x8 __attribute__((ext_vector_type(8)));
typedef unsigned short u16x8 __attribute__((ext_vector_type(8)));

__device__ __forceinline__ unsigned short f2bf(float f) {
    unsigned u = __float_as_uint(f);
    u += 0x7FFFu + ((u >> 16) & 1u);   // round-to-nearest-even
    return (unsigned short)(u >> 16);
}

// ---------------- problem constants ----------------
// B=64, C=80, IN_CH=300, J=8192, S=8, OUT=1024
// feature [64,2048,14,14] (131072 rows of 196 floats), out [64,80]

// ---------------- ws layout (bytes) ----------------
constexpr size_t OFF_FEATB = 0;          // 64*2048 bf16  = 262144
constexpr size_t OFF_X2B   = 262144;     // 80*1024 bf16  = 163840
constexpr size_t OFF_XB    = 425984;     // 80*2048 bf16  = 327680
constexpr size_t OFF_IMG   = 753664;     // 64*8192 f32   = 2097152
constexpr size_t OFF_CLS   = 2850816;    // 80*8192 f32   = 2621440
constexpr size_t OFF_G     = 5472256;    // 80*8192 f32   = 2621440
constexpr size_t OFF_Y0    = 8093696;    // 80*1024 f32   = 327680

// =================== roles (256 threads) ===================

// maxpool r16: LDS-staged linear copy, but with the staging split into
// LOADS-FIRST (7 named regs) then WRITES — so all 7 global loads are in
// flight before any vmcnt wait (R12-R14: compiler interleaved load+ds_write
// pairs, capping each wave at ~1 load in flight -> ~2 TB/s).
__device__ __forceinline__ void maxpool_role(int vbid, const float* __restrict__ feature,
                                             unsigned short* __restrict__ featb,
                                             float4* tile /* 1568 float4 */) {
    int t = threadIdx.x;
    const float4* src = (const float4*)(feature + (size_t)vbid * 32 * 196);
    float4 g[6];
    #pragma unroll
    for (int p = 0; p < 6; ++p) g[p] = src[p * 256 + t];
    float4 g6;
    if (t < 32) g6 = src[1536 + t];
    #pragma unroll
    for (int p = 0; p < 6; ++p) tile[p * 256 + t] = g[p];
    if (t < 32) tile[1536 + t] = g6;
    __syncthreads();

    int r = t >> 3, q = t & 7;                    // 32 rows x 8 threads
    const float4* row = tile + r * 49;
    float4 v0 = row[q],      v1 = row[q + 8],  v2 = row[q + 16];
    float4 v3 = row[q + 24], v4 = row[q + 32], v5 = row[q + 40];
    float m0 = fmaxf(fmaxf(v0.x, v0.y), fmaxf(v0.z, v0.w));
    float m1 = fmaxf(fmaxf(v1.x, v1.y), fmaxf(v1.z, v1.w));
    float m2 = fmaxf(fmaxf(v2.x, v2.y), fmaxf(v2.z, v2.w));
    float m3 = fmaxf(fmaxf(v3.x, v3.y), fmaxf(v3.z, v3.w));
    float m4 = fmaxf(fmaxf(v4.x, v4.y), fmaxf(v4.z, v4.w));
    float m5 = fmaxf(fmaxf(v5.x, v5.y), fmaxf(v5.z, v5.w));
    float m = fmaxf(fmaxf(fmaxf(m0, m1), fmaxf(m2, m3)), fmaxf(m4, m5));
    if (q == 0) {
        float4 d = row[48];
        m = fmaxf(m, fmaxf(fmaxf(d.x, d.y), fmaxf(d.z, d.w)));
    }
    #pragma unroll
    for (int off = 1; off < 8; off <<= 1) m = fmaxf(m, __shfl_xor(m, off));
    if (q == 0) featb[vbid * 32 + r] = f2bf(m);
}

// y0 role (R14 K-parallel, proven): idx in [0,320): c = idx>>2, j-quarter =
// idx&3. 256 thr = 4 k-slices (75 each) x 64 j-float4.
__device__ __forceinline__ void y0_role(int idx, const float* __restrict__ inp,
                                        const float* __restrict__ W1,
                                        float* __restrict__ y0g, float4* red) {
    int c = idx >> 2;
    int j = (idx & 3) * 256 + (threadIdx.x & 63) * 4;
    int ks = threadIdx.x >> 6;                    // 0..3
    const float* ir = inp + c * 300 + ks * 75;
    const float* wp = W1 + (size_t)(ks * 75) * 1024 + j;
    float4 acc = {0.f, 0.f, 0.f, 0.f};
    for (int k = 0; k < 75; k += 3) {
        float a0 = ir[k], a1 = ir[k + 1], a2 = ir[k + 2];
        float4 w0 = *(const float4*)(wp + (size_t)k * 1024);
        float4 w1 = *(const float4*)(wp + (size_t)(k + 1) * 1024);
        float4 w2 = *(const float4*)(wp + (size_t)(k + 2) * 1024);
        acc.x = fmaf(a0, w0.x, acc.x); acc.y = fmaf(a0, w0.y, acc.y);
        acc.z = fmaf(a0, w0.z, acc.z); acc.w = fmaf(a0, w0.w, acc.w);
        acc.x = fmaf(a1, w1.x, acc.x); acc.y = fmaf(a1, w1.y, acc.y);
        acc.z = fmaf(a1, w1.z, acc.z); acc.w = fmaf(a1, w1.w, acc.w);
        acc.x = fmaf(a2, w2.x, acc.x); acc.y = fmaf(a2, w2.y, acc.y);
        acc.z = fmaf(a2, w2.z, acc.z); acc.w = fmaf(a2, w2.w, acc.w);
    }
    int jq = threadIdx.x & 63;
    red[ks * 64 + jq] = __builtin_bit_cast(float4, acc);
    __syncthreads();
    if (ks == 0) {
        float4 s0 = red[jq], s1 = red[64 + jq], s2 = red[128 + jq], s3 = red[192 + jq];
        float4 s;
        s.x = s0.x + s1.x + s2.x + s3.x;
        s.y = s0.y + s1.y + s2.y + s3.y;
        s.z = s0.z + s1.z + s2.z + s3.z;
        s.w = s0.w + s1.w + s2.w + s3.w;
        *(float4*)(y0g + (size_t)c * 1024 + j) = s;
    }
}

// x1x2 role (R14, proven): K=80 chains only (A L1-resident, y0 from L2).
__device__ __forceinline__ void x1x2_role(int idx, const float* __restrict__ y0g,
                                          const float* __restrict__ A,
                                          unsigned short* __restrict__ x2b,
                                          float* smem) {
    float* dinv = smem;            // [80]
    float* ys   = smem + 80;       // [80][8]
    float* xs   = smem + 720;      // [80][8]
    int t = threadIdx.x;
    int j = t & 7, slot = t >> 3;
    int j0 = idx * 8;
    int c0 = slot, c1 = slot + 32, c2 = slot + 64;
    bool has3 = (slot < 16);                      // wave-uniform

    if (t < 80) {
        const float4* ar = (const float4*)(A + t * 80);
        float4 s4 = {0.f, 0.f, 0.f, 0.f};
        #pragma unroll
        for (int q = 0; q < 20; q++) {
            float4 v = ar[q];
            s4.x += v.x; s4.y += v.y; s4.z += v.z; s4.w += v.w;
        }
        dinv[t] = 1.0f / sqrtf(s4.x + s4.y + s4.z + s4.w);
    }
    __syncthreads();
    ys[c0 * 8 + j] = dinv[c0] * y0g[(size_t)c0 * 1024 + j0 + j];
    ys[c1 * 8 + j] = dinv[c1] * y0g[(size_t)c1 * 1024 + j0 + j];
    if (has3) ys[c2 * 8 + j] = dinv[c2] * y0g[(size_t)c2 * 1024 + j0 + j];
    __syncthreads();

    float b0 = 0.f, b1 = 0.f, b2 = 0.f;
    #pragma unroll 4
    for (int e = 0; e < 80; e++) {
        float y = ys[e * 8 + j];
        b0 = fmaf(A[e * 80 + c0], y, b0);
        b1 = fmaf(A[e * 80 + c1], y, b1);
        if (has3) b2 = fmaf(A[e * 80 + c2], y, b2);
    }
    b0 *= dinv[c0];
    b1 *= dinv[c1];
    b2 *= has3 ? dinv[c2] : 0.f;
    if (b0 < 0.f) b0 *= 0.2f;
    if (b1 < 0.f) b1 *= 0.2f;
    if (b2 < 0.f) b2 *= 0.2f;
    __syncthreads();
    xs[c0 * 8 + j] = dinv[c0] * b0;
    xs[c1 * 8 + j] = dinv[c1] * b1;
    if (has3) xs[c2 * 8 + j] = dinv[c2] * b2;
    __syncthreads();

    float d0 = 0.f, d1 = 0.f, d2 = 0.f;
    #pragma unroll 4
    for (int e = 0; e < 80; e++) {
        float x = xs[e * 8 + j];
        d0 = fmaf(A[e * 80 + c0], x, d0);
        d1 = fmaf(A[e * 80 + c1], x, d1);
        if (has3) d2 = fmaf(A[e * 80 + c2], x, d2);
    }
    x2b[c0 * 1024 + j0 + j] = f2bf(d0 * dinv[c0]);
    x2b[c1 * 1024 + j0 + j] = f2bf(d1 * dinv[c1]);
    if (has3) x2b[c2 * 1024 + j0 + j] = f2bf(d2 * dinv[c2]);
}

// =================== MFMA GEMMs (256 thr, BN=16, in-block 4-way K-split) ===================
template <int MF>
__device__ __forceinline__ void gemm_block(int bx, const unsigned short* __restrict__ X,
                                           const float* __restrict__ W,
                                           const float* __restrict__ bias,
                                           float* __restrict__ outf,
                                           unsigned short* __restrict__ outb,
                                           int N, int K, float (*red)[64][21]) {
    int tid = threadIdx.x;
    int ks = tid >> 6, lane = tid & 63;
    int n = bx * 16 + (lane & 15);
    int rowa = lane & 15;
    int koff = (lane >> 4) * 8;
    int Kc = K >> 2;
    int k0 = ks * Kc;

    f32x4 acc[MF];
    #pragma unroll
    for (int i = 0; i < MF; i++) acc[i] = (f32x4)(0.f);

    const float* wrow = W + (size_t)n * K;

    #pragma unroll 2
    for (int k = k0; k < k0 + Kc; k += 32) {
        float4 w0 = *(const float4*)(wrow + k + koff);
        float4 w1 = *(const float4*)(wrow + k + koff + 4);
        u16x8 bu;
        bu[0] = f2bf(w0.x); bu[1] = f2bf(w0.y); bu[2] = f2bf(w0.z); bu[3] = f2bf(w0.w);
        bu[4] = f2bf(w1.x); bu[5] = f2bf(w1.y); bu[6] = f2bf(w1.z); bu[7] = f2bf(w1.w);
        bf16x8 bf = __builtin_bit_cast(bf16x8, bu);
        #pragma unroll
        for (int mf = 0; mf < MF; mf++) {
            u16x8 au = *(const u16x8*)(X + (size_t)(mf * 16 + rowa) * K + k + koff);
            acc[mf] = __builtin_amdgcn_mfma_f32_16x16x32_bf16(
                __builtin_bit_cast(bf16x8, au), bf, acc[mf], 0, 0, 0);
        }
    }

    #pragma unroll
    for (int mf = 0; mf < MF; mf++)
        #pragma unroll
        for (int i = 0; i < 4; i++)
            red[ks][lane][mf * 4 + i] = acc[mf][i];
    __syncthreads();

    int lane2 = tid & 63, sg = tid >> 6;
    int n2 = bx * 16 + (lane2 & 15);
    float b = bias ? bias[n2] : 0.f;
    #pragma unroll
    for (int mf = 0; mf < MF; mf++) {
        int slot = mf * 4 + sg;
        float s = red[0][lane2][slot] + red[1][lane2][slot]
                + red[2][lane2][slot] + red[3][lane2][slot] + b;
        int row = mf * 16 + (lane2 >> 4) * 4 + sg;
        size_t o = (size_t)row * N + n2;
        if (outf) outf[o] = s;
        if (outb) outb[o] = f2bf(s);
    }
}

// W in [K][N] row-major: strided B loads — no transpose needed.
template <int MF>
__device__ __forceinline__ void gemm_block_kn(int bx, const unsigned short* __restrict__ X,
                                              const float* __restrict__ Wkn,
                                              const float* __restrict__ bias,
                                              float* __restrict__ outf,
                                              unsigned short* __restrict__ outb,
                                              int N, int K, float (*red)[64][21]) {
    int tid = threadIdx.x;
    int ks = tid >> 6, lane = tid & 63;
    int n = bx * 16 + (lane & 15);
    int rowa = lane & 15;
    int koff = (lane >> 4) * 8;
    int Kc = K >> 2;
    int k0 = ks * Kc;

    f32x4 acc[MF];
    #pragma unroll
    for (int i = 0; i < MF; i++) acc[i] = (f32x4)(0.f);

    #pragma unroll 2
    for (int k = k0; k < k0 + Kc; k += 32) {
        float w[8];
        #pragma unroll
        for (int i = 0; i < 8; i++) w[i] = Wkn[(size_t)(k + koff + i) * N + n];
        u16x8 bu;
        #pragma unroll
        for (int i = 0; i < 8; i++) bu[i] = f2bf(w[i]);
        bf16x8 bf = __builtin_bit_cast(bf16x8, bu);
        #pragma unroll
        for (int mf = 0; mf < MF; mf++) {
            u16x8 au = *(const u16x8*)(X + (size_t)(mf * 16 + rowa) * K + k + koff);
            acc[mf] = __builtin_amdgcn_mfma_f32_16x16x32_bf16(
                __builtin_bit_cast(bf16x8, au), bf, acc[mf], 0, 0, 0);
        }
    }

    #pragma unroll
    for (int mf = 0; mf < MF; mf++)
        #pragma unroll
        for (int i = 0; i < 4; i++)
            red[ks][lane][mf * 4 + i] = acc[mf][i];
    __syncthreads();

    int lane2 = tid & 63, sg = tid >> 6;
    int n2 = bx * 16 + (lane2 & 15);
    float b = bias ? bias[n2] : 0.f;
    #pragma unroll
    for (int mf = 0; mf < MF; mf++) {
        int slot = mf * 4 + sg;
        float s = red[0][lane2][slot] + red[1][lane2][slot]
                + red[2][lane2][slot] + red[3][lane2][slot] + b;
        int row = mf * 16 + (lane2 >> 4) * 4 + sg;
        size_t o = (size_t)row * N + n2;
        if (outf) outf[o] = s;
        if (outb) outb[o] = f2bf(s);
    }
}

// =================== kernels (6 dispatches) ===================

// A: y0 k-parallel (0-319) | maxpool (320-4415). LDS 25.1 KB -> 6 blocks/CU.
__global__ __launch_bounds__(256, 6) void kA(const float* __restrict__ feature,
                                             unsigned short* __restrict__ featb,
                                             const float* __restrict__ inp,
                                             const float* __restrict__ W1,
                                             float* __restrict__ y0g) {
    __shared__ __align__(16) float smem[6272];    // 25.1 KB union
    int b = blockIdx.x;
    if (b < 320) y0_role(b, inp, W1, y0g, (float4*)smem);
    else         maxpool_role(b - 320, feature, featb, (float4*)smem);
}

// B: x1x2 (0-127) | img units 0-383 (128-511)
__global__ __launch_bounds__(256, 4) void kB(const float* __restrict__ y0g,
                                             const float* __restrict__ A,
                                             unsigned short* __restrict__ x2b,
                                             const unsigned short* __restrict__ featb,
                                             const float* __restrict__ W_img,
                                             const float* __restrict__ b_img,
                                             float* __restrict__ img) {
    __shared__ __align__(16) float red[4][64][21];   // 21.5 KB
    int b = blockIdx.x;
    if (b < 128) x1x2_role(b, y0g, A, x2b, (float*)red);
    else         gemm_block<4>(b - 128, featb, W_img, b_img, img, nullptr, 8192, 2048, red);
}

// C: xb (0-127, [K][N] strided) | img units 384-511 (128-255)
__global__ __launch_bounds__(256, 4) void kC(const unsigned short* __restrict__ x2b,
                                             const float* __restrict__ W_gc2,
                                             unsigned short* __restrict__ xb,
                                             const unsigned short* __restrict__ featb,
                                             const float* __restrict__ W_img,
                                             const float* __restrict__ b_img,
                                             float* __restrict__ img) {
    __shared__ __align__(16) float red[4][64][21];
    int b = blockIdx.x;
    if (b < 128) gemm_block_kn<5>(b, x2b, W_gc2, nullptr, nullptr, xb, 2048, 1024, red);
    else         gemm_block<4>(b - 128 + 384, featb, W_img, b_img, img, nullptr, 8192, 2048, red);
}

// D: cls = xb @ W_cls^T + b_cls (512 blocks)
__global__ __launch_bounds__(256, 4) void kD(const unsigned short* __restrict__ xb,
                                             const float* __restrict__ W_cls,
                                             const float* __restrict__ b_cls,
                                             float* __restrict__ cls) {
    __shared__ __align__(16) float red[4][64][21];
    gemm_block<5>(blockIdx.x, xb, W_cls, b_cls, cls, nullptr, 8192, 2048, red);
}

// E: G[c2,j] = sum_c cls[c,j] * W_ml[c2, c*1024 + (j>>3)]; 640 blocks
__global__ __launch_bounds__(256, 4) void kE(const float* __restrict__ cls,
                                             const float* __restrict__ W_ml,
                                             float* __restrict__ G) {
    __shared__ __align__(16) float smem[8 * 80 * 16];   // 40 KB
    float (*wml)[80][16] = (float (*)[80][16])smem;
    int idx = blockIdx.x;
    int o0  = (idx & 63) * 16;
    int c2b = (idx >> 6) * 8;
    int j0  = o0 * 8;
    for (int i = threadIdx.x; i < 8 * 80 * 16; i += 256) {
        int ol = i & 15, c = (i >> 4) % 80, c2 = i / 1280;
        wml[c2][c][ol] = W_ml[(size_t)(c2b + c2) * 81920 + c * 1024 + o0 + ol];
    }
    __syncthreads();
    int jl  = threadIdx.x & 127;
    int c2h = (threadIdx.x >> 7) * 4;
    int ol  = jl >> 3;
    float acc[4] = {0.f, 0.f, 0.f, 0.f};
    for (int c = 0; c < 80; c++) {
        float cv = cls[(size_t)c * 8192 + j0 + jl];
        #pragma unroll
        for (int i = 0; i < 4; i++) acc[i] = fmaf(cv, wml[c2h + i][c][ol], acc[i]);
    }
    #pragma unroll
    for (int i = 0; i < 4; i++) G[(size_t)(c2b + c2h + i) * 8192 + j0 + jl] = acc[i];
}

// F: out[b,c2] = sum_j img[b,j]*G[c2,j] + b_ml[c2]; 640 blocks
__global__ __launch_bounds__(256, 2) void kF(const float* __restrict__ img,
                                             const float* __restrict__ G,
                                             const float* __restrict__ b_ml,
                                             float* __restrict__ out) {
    __shared__ float sm[4][8];
    int b = blockIdx.x / 10, cg = blockIdx.x % 10;
    int kc = threadIdx.x >> 6, lane = threadIdx.x & 63;
    const float* ib = img + (size_t)b * 8192 + kc * 2048;
    const float* gb = G + (size_t)(cg * 8) * 8192 + kc * 2048;
    float acc[8] = {0.f, 0.f, 0.f, 0.f, 0.f, 0.f, 0.f, 0.f};
    #pragma unroll
    for (int step = 0; step < 8; step++) {
        int k = step * 256 + lane * 4;
        float4 iv = *(const float4*)(ib + k);
        float4 gv[8];
        #pragma unroll
        for (int i = 0; i < 8; i++) gv[i] = *(const float4*)(gb + (size_t)i * 8192 + k);
        #pragma unroll
        for (int i = 0; i < 8; i++) {
            acc[i] = fmaf(iv.x, gv[i].x, acc[i]);
            acc[i] = fmaf(iv.y, gv[i].y, acc[i]);
            acc[i] = fmaf(iv.z, gv[i].z, acc[i]);
            acc[i] = fmaf(iv.w, gv[i].w, acc[i]);
        }
    }
    #pragma unroll
    for (int i = 0; i < 8; i++) {
        float v = acc[i];
        #pragma unroll
        for (int off = 32; off; off >>= 1) v += __shfl_xor(v, off);
        if (lane == 0) sm[kc][i] = v;
    }
    __syncthreads();
    if (threadIdx.x < 8) {
        int i = threadIdx.x;
        float s = b_ml[cg * 8 + i] + sm[0][i] + sm[1][i] + sm[2][i] + sm[3][i];
        out[(size_t)b * 80 + cg * 8 + i] = s;
    }
}

// ---------------- launch ----------------
extern "C" void kernel_launch(void* const* d_in, const int* in_sizes, int n_in,
                              void* d_out, int out_size, void* d_ws, size_t ws_size,
                              hipStream_t stream) {
    (void)in_sizes; (void)n_in; (void)out_size; (void)ws_size;
    const float* feature = (const float*)d_in[0];
    const float* inp     = (const float*)d_in[1];
    const float* A       = (const float*)d_in[2];
    const float* W_gc1   = (const float*)d_in[3];
    const float* W_gc2   = (const float*)d_in[4];
    const float* W_img   = (const float*)d_in[5];
    const float* b_img   = (const float*)d_in[6];
    const float* W_cls   = (const float*)d_in[7];
    const float* b_cls   = (const float*)d_in[8];
    const float* W_ml    = (const float*)d_in[9];
    const float* b_ml    = (const float*)d_in[10];
    float* out = (float*)d_out;
    char*  ws  = (char*)d_ws;

    unsigned short* featb = (unsigned short*)(ws + OFF_FEATB);
    unsigned short* x2b   = (unsigned short*)(ws + OFF_X2B);
    unsigned short* xb    = (unsigned short*)(ws + OFF_XB);
    float* img  = (float*)(ws + OFF_IMG);
    float* cls  = (float*)(ws + OFF_CLS);
    float* G    = (float*)(ws + OFF_G);
    float* y0g  = (float*)(ws + OFF_Y0);

    kA<<<4416, 256, 0, stream>>>(feature, featb, inp, W_gc1, y0g);
    kB<<<512,  256, 0, stream>>>(y0g, A, x2b, featb, W_img, b_img, img);
    kC<<<256,  256, 0, stream>>>(x2b, W_gc2, xb, featb, W_img, b_img, img);
    kD<<<512,  256, 0, stream>>>(xb, W_cls, b_cls, cls);
    kE<<<640,  256, 0, stream>>>(cls, W_ml, G);
    kF<<<640,  256, 0, stream>>>(img, G, b_ml, out);
}